// Round 10
// baseline (1151.092 us; speedup 1.0000x reference)
//
#include <hip/hip_runtime.h>
#include <hip/hip_bf16.h>

#define INF 385
#define HD 128
#define NWG 16   // workgroups per histogram group
#define HIST_BLOCKS (10 * NWG)

typedef __attribute__((ext_vector_type(8))) short short8;
typedef __attribute__((ext_vector_type(4))) float f32x4;

__device__ inline unsigned short f2b(float f) {
    __hip_bfloat16 h = __float2bfloat16(f);
    return *reinterpret_cast<unsigned short*>(&h);
}
__device__ inline float b2f(unsigned int lo16) {
    union { unsigned int u; float f; } c; c.u = lo16 << 16; return c.f;
}

// ---------------- convert body: feat f32 [N][385] -> bf16 [N][384] + alast ----------------
__device__ __forceinline__ void convert_body(
    const float* f0, const float* f1, const float* f2, const float* f3,
    unsigned int* featB, float* alast, int N, int gid, int nthr)
{
    int per = N * 192;
    int tot = 4 * per;
    for (int p = gid; p < tot; p += nthr) {
        int t = p / per, rem = p - t * per;
        int n = rem / 192, c2 = (rem - n * 192) * 2;
        const float* f = (t < 2) ? (t == 0 ? f0 : f1) : (t == 2 ? f2 : f3);
        const float* row = f + (size_t)n * INF;
        float a = row[c2], b = row[c2 + 1];
        featB[p] = ((unsigned int)f2b(b) << 16) | f2b(a);
    }
    for (int p = gid; p < 4 * N; p += nthr) {
        int t = p / N, n = p - t * N;
        const float* f = (t < 2) ? (t == 0 ? f0 : f1) : (t == 2 ? f2 : f3);
        alast[p] = f[(size_t)n * INF + 384];
    }
}

// ---------------- fused: LDS-privatized histogram (blocks<HIST_BLOCKS) + convert ----------------
__global__ __launch_bounds__(1024) void hist_conv_kernel(
    const int* __restrict__ src_all, const int* __restrict__ dst_all,
    unsigned short* __restrict__ partial,    // [10][NWG][N]
    unsigned short* __restrict__ rank_local, // [5][E]
    int E, int N,
    const float* __restrict__ f0, const float* __restrict__ f1,
    const float* __restrict__ f2, const float* __restrict__ f3,
    unsigned int* __restrict__ featB, float* __restrict__ alast)
{
    __shared__ unsigned int cnt[25000];      // 2 packed ushort counters per uint
    int tid = threadIdx.x;
    if (blockIdx.x >= HIST_BLOCKS) {
        int nconv = gridDim.x - HIST_BLOCKS;
        convert_body(f0, f1, f2, f3, featB, alast, N,
                     (blockIdx.x - HIST_BLOCKS) * 1024 + tid, nconv * 1024);
        return;
    }
    int g = blockIdx.x / NWG;
    int w = blockIdx.x % NWG;
    int half = (N + 1) / 2;
    for (int i = tid; i < half; i += 1024) cnt[i] = 0;
    __syncthreads();

    int C = (E + NWG - 1) / NWG;
    int lo = w * C, hi = min(lo + C, E);
    if (g < 5) {
        const int* arr = dst_all + (size_t)g * E;
        for (int e = lo + tid; e < hi; e += 1024) {
            int d = __builtin_nontemporal_load(&arr[e]);
            unsigned int sh = (d & 1) * 16;
            unsigned int old = atomicAdd(&cnt[d >> 1], 1u << sh);
            rank_local[(size_t)g * E + e] = (unsigned short)((old >> sh) & 0xffffu);
        }
    } else {
        const int* arr = src_all + (size_t)(g - 5) * E;
        for (int e = lo + tid; e < hi; e += 1024) {
            int d = __builtin_nontemporal_load(&arr[e]);
            atomicAdd(&cnt[d >> 1], 1u << ((d & 1) * 16));
        }
    }
    __syncthreads();
    unsigned short* outp = partial + ((size_t)g * NWG + w) * N;
    for (int n = tid; n < N; n += 1024)
        outp[n] = (unsigned short)((cnt[n >> 1] >> ((n & 1) * 16)) & 0xffffu);
}

// ---------------- reduce partials -> degrees/rsqrt; in-place exclusive prefix over chunks ----------------
__global__ void reduce_kernel(unsigned short* __restrict__ partial, int* __restrict__ cnt_dst,
                              float* __restrict__ rsq_out, float* __restrict__ rsq_in, int N) {
    int i = blockIdx.x * blockDim.x + threadIdx.x;
    int stride = gridDim.x * blockDim.x;
    int tot = 10 * N;
    for (; i < tot; i += stride) {
        int g = i / N, n = i - g * N;
        unsigned short* p = partial + ((size_t)g * NWG) * N + n;
        int sum = 0;
        #pragma unroll
        for (int w = 0; w < NWG; ++w) {
            int v = p[(size_t)w * N];
            p[(size_t)w * N] = (unsigned short)sum;   // exclusive prefix (rank base per chunk)
            sum += v;
        }
        float r = rsqrtf((float)max(sum, 1));
        if (g < 5) { cnt_dst[i] = sum; rsq_in[i] = r; }
        else rsq_out[i - 5 * N] = r;
    }
}

// 5 blocks, one per etype
__global__ __launch_bounds__(1024) void scan_kernel(const int* __restrict__ cnt_all,
                                                    int* __restrict__ off_all, int n) {
    const int* cnt = cnt_all + (size_t)blockIdx.x * n;
    int* off = off_all + (size_t)blockIdx.x * (n + 1);
    __shared__ int ssum[1024];
    int t = threadIdx.x;
    int chunk = (n + 1023) / 1024;
    int lo = t * chunk, hi = min(lo + chunk, n);
    int s = 0;
    for (int i = lo; i < hi; ++i) s += cnt[i];
    ssum[t] = s;
    __syncthreads();
    for (int d = 1; d < 1024; d <<= 1) {
        int v = (t >= d) ? ssum[t - d] : 0;
        __syncthreads();
        ssum[t] += v;
        __syncthreads();
    }
    int excl = (t == 0) ? 0 : ssum[t - 1];
    for (int i = lo; i < hi; ++i) { off[i] = excl; excl += cnt[i]; }
    if (t == 1023) off[n] = ssum[1023];
}

// ---------------- XCD-localized atomic-free permutation ----------------
// Block b -> XCD b&7 (dispatch heuristic). etype regions (3.2MB) then stay in 1-2 L2s.
// xcd->etype: {0,1,2,3,4,0,1,2}; e0-2 get 2 XCD groups, e3-4 get 1.
__global__ __launch_bounds__(256) void permute_kernel(
    const int* __restrict__ src_all, const int* __restrict__ dst_all,
    const int* __restrict__ off, const unsigned short* __restrict__ partial,
    const unsigned short* __restrict__ rank_local,
    unsigned short* __restrict__ sorted, int E, int N)
{
    int b = blockIdx.x;
    int xcd = b & 7;
    int k = (xcd < 5) ? xcd : xcd - 5;
    int sub = (xcd >= 5) ? 1 : 0;
    int nGroups = (k < 3) ? 2 : 1;
    int blocksPerXcd = gridDim.x >> 3;              // grid multiple of 8
    int tid_in_xcd = (b >> 3) * 256 + threadIdx.x;  // 0 .. blocksPerXcd*256-1
    int e = sub * (blocksPerXcd * 256) + tid_in_xcd;
    int nthr = nGroups * blocksPerXcd * 256;
    int C = (E + NWG - 1) / NWG;

    const int* dsts = dst_all + (size_t)k * E;
    const int* srcs = src_all + (size_t)k * E;
    const unsigned short* rl = rank_local + (size_t)k * E;
    const int* offk = off + (size_t)k * (N + 1);
    const unsigned short* pk = partial + (size_t)k * NWG * N;
    unsigned short* sk = sorted + (size_t)k * E;

    for (; e < E; e += nthr) {
        int w = e / C;
        int d = __builtin_nontemporal_load(&dsts[e]);
        int s = __builtin_nontemporal_load(&srcs[e]);
        int r = __builtin_nontemporal_load(&rl[e]);
        int pos = offk[d] + pk[(size_t)w * N + d] + r;
        sk[pos] = (unsigned short)s;                 // cached store: let L2 accumulate lines
    }
}

// ---------------- feat convert (standalone, fallback path) ----------------
__global__ void convert_kernel(const float* __restrict__ f0, const float* __restrict__ f1,
                               const float* __restrict__ f2, const float* __restrict__ f3,
                               unsigned int* __restrict__ featB, float* __restrict__ alast, int N) {
    convert_body(f0, f1, f2, f3, featB, alast, N,
                 blockIdx.x * blockDim.x + threadIdx.x, gridDim.x * blockDim.x);
}

// ---------------- weight prep: transpose + bf16, combined biases ----------------
__global__ void prep_weights_kernel(const float* __restrict__ Wp,
                                    const float* __restrict__ Wc1, const float* __restrict__ Wc2,
                                    const float* __restrict__ bc1, const float* __restrict__ bc2,
                                    unsigned short* __restrict__ WpT,
                                    unsigned short* __restrict__ WcT,
                                    float* __restrict__ cbias) {
    int i = blockIdx.x * blockDim.x + threadIdx.x;
    int stride = gridDim.x * blockDim.x;
    const int nWp = 4 * 128 * 384;
    for (int p = i; p < nWp; p += stride) {
        int t = p / (128 * 384), rem = p % (128 * 384);
        int c = rem / 384, k = rem % 384;
        WpT[p] = f2b(Wp[(size_t)t * INF * HD + (size_t)k * HD + c]);
    }
    const int nWc = 5 * 128 * 128;
    for (int p = i; p < 2 * nWc; p += stride) {
        int layer = p / nWc, rem = p % nWc;
        int e = rem / (128 * 128), rem2 = rem % (128 * 128);
        int c = rem2 / 128, k = rem2 % 128;
        const float* W = layer ? Wc2 : Wc1;
        WcT[p] = f2b(W[(size_t)e * 128 * 128 + (size_t)k * 128 + c]);
    }
    // cbias[layer][t][c]: t0<-bc[4], t1<-bc[0], t2<-bc[2]+bc[3], t3<-bc[1]
    for (int p = i; p < 2 * 4 * 128; p += stride) {
        int layer = p / 512, rem = p % 512;
        int t = rem / 128, c = rem % 128;
        const float* bc = layer ? bc2 : bc1;
        float v;
        if (t == 0) v = bc[4 * 128 + c];
        else if (t == 1) v = bc[0 * 128 + c];
        else if (t == 2) v = bc[2 * 128 + c] + bc[3 * 128 + c];
        else v = bc[1 * 128 + c];
        cbias[p] = v;
    }
}

// ---------------- batched MFMA GEMM (bf16 A), optional rank-1 / bias / rowscale ----------------
struct GemmDesc {
    const unsigned short* A;      // [M][lda] bf16, rows 16B-aligned
    const unsigned short* Bt;     // [128][K] bf16
    const float* bias;            // [128] or null
    const float* rowscale;        // [M] or null
    const float* alast;           // [M] or null (rank-1 left vector)
    const float* wlast;           // [128] or null (rank-1 right vector)
    unsigned short* out;          // [M][128] bf16
};
struct GemmBatch { GemmDesc d[5]; };

__global__ __launch_bounds__(256) void gemm_mfma_kernel(
    GemmBatch batch, int lda, int M, int K, int relu)
{
    const GemmDesc dsc = batch.d[blockIdx.y];
    const unsigned short* __restrict__ Bt = dsc.Bt;
    const unsigned short* __restrict__ A = dsc.A;

    __shared__ __align__(16) unsigned short As[64][72];   // +8 pad: 144B row stride
    __shared__ __align__(16) unsigned short Bs[128][72];
    const int tid = threadIdx.x;
    const int bm = blockIdx.x * 64;
    const int wid = tid >> 6, lane = tid & 63;
    const int wr = wid & 1, wc = wid >> 1;      // 2x2 wave grid: 32 rows x 64 cols each
    const int l15 = lane & 15, l4 = lane >> 4;

    f32x4 acc[2][4] = {};

    for (int k0 = 0; k0 < K; k0 += 64) {
        {
            int r = tid >> 2, q = tid & 3;      // 16 bf16 per thread, vectorized
            int gm = bm + r;
            if (gm < M) {
                const uint4* g = (const uint4*)(A + (size_t)gm * lda + k0 + q * 16);
                *(uint4*)&As[r][q * 16] = g[0];
                *(uint4*)&As[r][q * 16 + 8] = g[1];
            } else {
                uint4 z = {0, 0, 0, 0};
                *(uint4*)&As[r][q * 16] = z;
                *(uint4*)&As[r][q * 16 + 8] = z;
            }
        }
        {
            int col = tid >> 1, hf = tid & 1;   // 32 bf16 per thread from Bt[col][k0+hf*32..]
            const uint4* g = (const uint4*)(Bt + (size_t)col * K + k0 + hf * 32);
            #pragma unroll
            for (int j = 0; j < 4; ++j)
                *(uint4*)&Bs[col][hf * 32 + j * 8] = g[j];
        }
        __syncthreads();
        #pragma unroll
        for (int kk = 0; kk < 2; ++kk) {
            short8 a[2], b[4];
            #pragma unroll
            for (int mi = 0; mi < 2; ++mi)
                a[mi] = *(const short8*)&As[wr * 32 + mi * 16 + l15][kk * 32 + l4 * 8];
            #pragma unroll
            for (int ni = 0; ni < 4; ++ni)
                b[ni] = *(const short8*)&Bs[wc * 64 + ni * 16 + l15][kk * 32 + l4 * 8];
            #pragma unroll
            for (int mi = 0; mi < 2; ++mi)
                #pragma unroll
                for (int ni = 0; ni < 4; ++ni)
                    acc[mi][ni] = __builtin_amdgcn_mfma_f32_16x16x32_bf16(
                        a[mi], b[ni], acc[mi][ni], 0, 0, 0);
        }
        __syncthreads();
    }

    // epilogue: C/D layout col=lane&15, row=(lane>>4)*4+reg  [m89-verified]
    #pragma unroll
    for (int mi = 0; mi < 2; ++mi) {
        #pragma unroll
        for (int r = 0; r < 4; ++r) {
            int grow = bm + wr * 32 + mi * 16 + l4 * 4 + r;
            if (grow >= M) continue;
            float rs = dsc.rowscale ? dsc.rowscale[grow] : 1.f;
            float al = dsc.alast ? dsc.alast[grow] : 0.f;
            #pragma unroll
            for (int ni = 0; ni < 4; ++ni) {
                int gcol = wc * 64 + ni * 16 + l15;
                float v = acc[mi][ni][r];
                if (dsc.wlast) v += al * dsc.wlast[gcol];
                if (dsc.bias) v += dsc.bias[gcol];
                v *= rs;
                if (relu) v = fmaxf(v, 0.f);
                dsc.out[(size_t)grow * HD + gcol] = f2b(v);
            }
        }
    }
}

// ---------------- batched CSR gather: wide loads ----------------
// Wave = 4 x 16-lane groups; group `sub` handles edges e+r*4+sub, each lane loads
// uint4 (8 bf16 channels l16*8..+8). Cross-sub combine via shfl_xor(16|32).
struct GatherDesc {
    const unsigned short* msgA; const unsigned short* sortedA;
    const int* offA; const float* rsqA;
    const unsigned short* msgB; const unsigned short* sortedB;  // null if single
    const int* offB; const float* rsqB;
    const float* bias; void* out;
};
struct GatherBatch { GatherDesc d[4]; };

__device__ __forceinline__ void accum8(uint4 v, float* acc) {
    acc[0] += b2f(v.x & 0xffffu); acc[1] += b2f(v.x >> 16);
    acc[2] += b2f(v.y & 0xffffu); acc[3] += b2f(v.y >> 16);
    acc[4] += b2f(v.z & 0xffffu); acc[5] += b2f(v.z >> 16);
    acc[6] += b2f(v.w & 0xffffu); acc[7] += b2f(v.w >> 16);
}

__device__ __forceinline__ void gather_seg(
    const unsigned short* __restrict__ msg, const unsigned short* __restrict__ sorted,
    int beg, int end, int sub, int lbyte, float* acc)
{
    const char* mbase = (const char*)msg;
    int e = beg;
    for (; e + 16 <= end; e += 16) {            // full chunks: 16 edges, 4 loads/lane
        uint4 v[4];
        #pragma unroll
        for (int r = 0; r < 4; ++r) {
            int s = sorted[e + r * 4 + sub];
            v[r] = *(const uint4*)(mbase + (size_t)s * 256 + lbyte);
        }
        #pragma unroll
        for (int r = 0; r < 4; ++r) accum8(v[r], acc);
    }
    if (e < end) {                               // masked tail chunk
        #pragma unroll
        for (int r = 0; r < 4; ++r) {
            int idx = e + r * 4 + sub;
            if (idx < end) {
                int s = sorted[idx];
                uint4 v = *(const uint4*)(mbase + (size_t)s * 256 + lbyte);
                accum8(v, acc);
            }
        }
    }
}

template<int OUT_BF16>
__global__ __launch_bounds__(256) void gather_kernel(GatherBatch batch, int n)
{
    const GatherDesc d = batch.d[blockIdx.y];
    int node = blockIdx.x * 4 + (threadIdx.x >> 6);   // wave-uniform
    if (node >= n) return;
    int lane = threadIdx.x & 63;
    int sub = lane >> 4;
    int l16 = lane & 15;
    int lbyte = l16 * 16;

    float comb[8];
    {
        float acc[8] = {};
        gather_seg(d.msgA, d.sortedA, d.offA[node], d.offA[node + 1], sub, lbyte, acc);
        float rA = d.rsqA[node];
        if (d.msgB) {
            float acc2[8] = {};
            gather_seg(d.msgB, d.sortedB, d.offB[node], d.offB[node + 1], sub, lbyte, acc2);
            float rB = d.rsqB[node];
            #pragma unroll
            for (int c = 0; c < 8; ++c) comb[c] = acc[c] * rA + acc2[c] * rB;
        } else {
            #pragma unroll
            for (int c = 0; c < 8; ++c) comb[c] = acc[c] * rA;
        }
    }
    #pragma unroll
    for (int c = 0; c < 8; ++c) {
        comb[c] += __shfl_xor(comb[c], 16);
        comb[c] += __shfl_xor(comb[c], 32);
    }
    if (sub == 0) {
        const float* bptr = d.bias + l16 * 8;
        float4 b0 = *(const float4*)bptr;
        float4 b1 = *(const float4*)(bptr + 4);
        float o[8] = {comb[0] + b0.x, comb[1] + b0.y, comb[2] + b0.z, comb[3] + b0.w,
                      comb[4] + b1.x, comb[5] + b1.y, comb[6] + b1.z, comb[7] + b1.w};
        #pragma unroll
        for (int c = 0; c < 8; ++c) o[c] = fmaxf(o[c], 0.f);
        if (OUT_BF16) {
            uint4 pv;
            pv.x = ((unsigned int)f2b(o[1]) << 16) | f2b(o[0]);
            pv.y = ((unsigned int)f2b(o[3]) << 16) | f2b(o[2]);
            pv.z = ((unsigned int)f2b(o[5]) << 16) | f2b(o[4]);
            pv.w = ((unsigned int)f2b(o[7]) << 16) | f2b(o[6]);
            *(uint4*)((char*)d.out + (size_t)node * 256 + lbyte) = pv;
        } else {
            float4 f0 = {o[0], o[1], o[2], o[3]};
            float4 f1 = {o[4], o[5], o[6], o[7]};
            float4* op = (float4*)((char*)d.out + (size_t)node * 512 + (size_t)l16 * 32);
            op[0] = f0; op[1] = f1;
        }
    }
}

extern "C" void kernel_launch(void* const* d_in, const int* in_sizes, int n_in,
                              void* d_out, int out_size, void* d_ws, size_t ws_size,
                              hipStream_t stream)
{
    const float* feat[4] = {(const float*)d_in[0], (const float*)d_in[1],
                            (const float*)d_in[2], (const float*)d_in[3]};
    const int* src_all = (const int*)d_in[4];
    const int* dst_all = (const int*)d_in[5];
    const float* Wp  = (const float*)d_in[6];
    const float* bp  = (const float*)d_in[7];
    const float* Wc1 = (const float*)d_in[8];
    const float* bc1 = (const float*)d_in[9];
    const float* Wc2 = (const float*)d_in[10];
    const float* bc2 = (const float*)d_in[11];

    const int N = in_sizes[0] / INF;      // 50000  (< 65536: ushort ids)
    const int E = in_sizes[4] / 5;        // 1,600,000

    // etypes: k -> (src_type, dst_type): (0,1) (1,3) (3,2) (0,2) (2,0)
    const int st_[5] = {0, 1, 3, 0, 2};

    // ---- workspace layout (256B-aligned) ----
    char* w = (char*)d_ws;
    auto take = [&](size_t bytes) { char* p = w; w += (bytes + 255) & ~(size_t)255; return p; };
    int*   cnt_dst = (int*)take(5 * (size_t)N * 4);
    float* rsq_out = (float*)take(5 * (size_t)N * 4);
    float* rsq_in  = (float*)take(5 * (size_t)N * 4);
    int*   off     = (int*)take(5 * (size_t)(N + 1) * 4);
    unsigned short* sorted = (unsigned short*)take(5 * (size_t)E * 2);  // 16 MB, live whole pass
    float* alast   = (float*)take(4 * (size_t)N * 4);
    unsigned short* WpT = (unsigned short*)take(4 * 128 * 384 * 2);
    unsigned short* WcT = (unsigned short*)take(2 * 5 * 128 * 128 * 2);
    float* cbias   = (float*)take(2 * 4 * 128 * 4);

    const size_t pr_bytes = 10u * NWG * (size_t)N * 2 + 5 * (size_t)E * 2;  // partial+rank (32MB)
    const size_t blob_sz = 4 * (size_t)N * 384 * 2;                         // featB (153.6MB)
    size_t fixed_used = (size_t)(w - (char*)d_ws);
    bool roomy = ws_size >= fixed_used + pr_bytes + blob_sz + (1u << 20);

    unsigned short *partial, *rank_local, *featB, *msg;
    if (roomy) {
        partial    = (unsigned short*)take(10u * NWG * (size_t)N * 2);
        rank_local = (unsigned short*)take(5 * (size_t)E * 2);
        char* blob = (char*)take(blob_sz);
        featB = (unsigned short*)blob;
        msg   = (unsigned short*)blob;   // overlays featB after proj
    } else {
        char* blob = (char*)take(blob_sz);
        partial    = (unsigned short*)blob;
        rank_local = (unsigned short*)(blob + 10u * NWG * (size_t)N * 2);
        featB      = (unsigned short*)blob;
        msg        = (unsigned short*)(blob + 32u * 1024 * 1024);
    }
    // h0 in d_out lower half (bf16), h1 in d_out upper half (bf16); both dead
    // before layer-2 gathers write f32 over the full d_out.
    unsigned short* h0 = (unsigned short*)d_out;
    unsigned short* h1 = (unsigned short*)d_out + 4 * (size_t)N * HD;

    const int gblk = (N + 63) / 64;

    prep_weights_kernel<<<512, 256, 0, stream>>>(Wp, Wc1, Wc2, bc1, bc2, WpT, WcT, cbias);

    // hist (160 blocks) || convert (512 blocks if roomy) in one dispatch
    hist_conv_kernel<<<roomy ? HIST_BLOCKS + 512 : HIST_BLOCKS, 1024, 0, stream>>>(
        src_all, dst_all, partial, rank_local, E, N,
        feat[0], feat[1], feat[2], feat[3], (unsigned int*)featB, alast);
    reduce_kernel<<<(10 * N + 255) / 256, 256, 0, stream>>>(partial, cnt_dst, rsq_out, rsq_in, N);
    scan_kernel<<<5, 1024, 0, stream>>>(cnt_dst, off, N);
    permute_kernel<<<2048, 256, 0, stream>>>(src_all, dst_all, off, partial, rank_local,
                                             sorted, E, N);
    if (!roomy)
        convert_kernel<<<2048, 256, 0, stream>>>(feat[0], feat[1], feat[2], feat[3],
                                                 (unsigned int*)featB, alast, N);

    // ---- input projections (batched over 4 types) ----
    {
        GemmBatch pb = {};
        for (int t = 0; t < 4; ++t) {
            pb.d[t].A = featB + (size_t)t * N * 384;
            pb.d[t].Bt = WpT + (size_t)t * 128 * 384;
            pb.d[t].bias = bp + (size_t)t * HD;
            pb.d[t].rowscale = nullptr;
            pb.d[t].alast = alast + (size_t)t * N;
            pb.d[t].wlast = Wp + (size_t)t * INF * HD + 384 * HD;
            pb.d[t].out = h0 + (size_t)t * N * HD;
        }
        gemm_mfma_kernel<<<dim3(gblk, 4), 256, 0, stream>>>(pb, 384, N, 384, 1);
    }

    // ---- 2 hetero conv layers ----
    for (int layer = 0; layer < 2; ++layer) {
        const unsigned short* hin = layer ? h1 : h0;
        const unsigned short* WT = WcT + (size_t)layer * 5 * 128 * 128;
        const float* cb = cbias + (size_t)layer * 4 * 128;

        // 5 independent conv GEMMs in one dispatch
        {
            GemmBatch cbch = {};
            for (int k = 0; k < 5; ++k) {
                cbch.d[k].A = hin + (size_t)st_[k] * N * HD;
                cbch.d[k].Bt = WT + (size_t)k * 128 * 128;
                cbch.d[k].bias = nullptr;
                cbch.d[k].rowscale = rsq_out + (size_t)k * N;
                cbch.d[k].alast = nullptr;
                cbch.d[k].wlast = nullptr;
                cbch.d[k].out = msg + (size_t)k * N * HD;
            }
            gemm_mfma_kernel<<<dim3(gblk, 5), 256, 0, stream>>>(cbch, HD, N, 128, 0);
        }

        // 4 gathers (k2+k3 dual into t2) in one dispatch
        {
            auto S = [&](int k) { return sorted + (size_t)k * E; };
            auto O = [&](int k) { return off + (size_t)k * (N + 1); };
            auto R = [&](int k) { return rsq_in + (size_t)k * N; };
            auto M_ = [&](int k) { return msg + (size_t)k * N * HD; };
            const int ksA[4] = {0, 1, 2, 4};
            const int dt [4] = {1, 3, 2, 0};
            GatherBatch gb = {};
            for (int y = 0; y < 4; ++y) {
                int k = ksA[y];
                gb.d[y].msgA = M_(k); gb.d[y].sortedA = S(k);
                gb.d[y].offA = O(k);  gb.d[y].rsqA = R(k);
                gb.d[y].msgB = nullptr; gb.d[y].sortedB = nullptr;
                gb.d[y].offB = nullptr; gb.d[y].rsqB = nullptr;
                gb.d[y].bias = cb + (size_t)dt[y] * HD;
                if (layer == 0)
                    gb.d[y].out = h1 + (size_t)dt[y] * N * HD;
                else
                    gb.d[y].out = (float*)d_out + (size_t)dt[y] * N * HD;
            }
            gb.d[2].msgB = M_(3); gb.d[2].sortedB = S(3);
            gb.d[2].offB = O(3);  gb.d[2].rsqB = R(3);
            const int gg = (N + 3) / 4;
            if (layer == 0)
                gather_kernel<1><<<dim3(gg, 4), 256, 0, stream>>>(gb, N);
            else
                gather_kernel<0><<<dim3(gg, 4), 256, 0, stream>>>(gb, N);
        }
    }
}

// Round 11
// 1111.817 us; speedup vs baseline: 1.0353x; 1.0353x over previous
//
#include <hip/hip_runtime.h>
#include <hip/hip_bf16.h>

#define INF 385
#define HD 128
#define NWG 16   // workgroups per histogram group
#define HIST_BLOCKS (10 * NWG)

typedef __attribute__((ext_vector_type(8))) short short8;
typedef __attribute__((ext_vector_type(4))) float f32x4;

__device__ inline unsigned short f2b(float f) {
    __hip_bfloat16 h = __float2bfloat16(f);
    return *reinterpret_cast<unsigned short*>(&h);
}
__device__ inline float b2f(unsigned int lo16) {
    union { unsigned int u; float f; } c; c.u = lo16 << 16; return c.f;
}

// ---------------- convert body: feat f32 [N][385] -> bf16 [N][384] + alast ----------------
__device__ __forceinline__ void convert_body(
    const float* f0, const float* f1, const float* f2, const float* f3,
    unsigned int* featB, float* alast, int N, int gid, int nthr)
{
    int per = N * 192;
    int tot = 4 * per;
    for (int p = gid; p < tot; p += nthr) {
        int t = p / per, rem = p - t * per;
        int n = rem / 192, c2 = (rem - n * 192) * 2;
        const float* f = (t < 2) ? (t == 0 ? f0 : f1) : (t == 2 ? f2 : f3);
        const float* row = f + (size_t)n * INF;
        float a = row[c2], b = row[c2 + 1];
        featB[p] = ((unsigned int)f2b(b) << 16) | f2b(a);
    }
    for (int p = gid; p < 4 * N; p += nthr) {
        int t = p / N, n = p - t * N;
        const float* f = (t < 2) ? (t == 0 ? f0 : f1) : (t == 2 ? f2 : f3);
        alast[p] = f[(size_t)n * INF + 384];
    }
}

// ---------------- fused: LDS-privatized histogram (blocks<HIST_BLOCKS) + convert ----------------
__global__ __launch_bounds__(1024) void hist_conv_kernel(
    const int* __restrict__ src_all, const int* __restrict__ dst_all,
    unsigned short* __restrict__ partial,    // [10][NWG][N]
    unsigned short* __restrict__ rank_local, // [5][E]
    int E, int N,
    const float* __restrict__ f0, const float* __restrict__ f1,
    const float* __restrict__ f2, const float* __restrict__ f3,
    unsigned int* __restrict__ featB, float* __restrict__ alast)
{
    __shared__ unsigned int cnt[25000];      // 2 packed ushort counters per uint
    int tid = threadIdx.x;
    if (blockIdx.x >= HIST_BLOCKS) {
        int nconv = gridDim.x - HIST_BLOCKS;
        convert_body(f0, f1, f2, f3, featB, alast, N,
                     (blockIdx.x - HIST_BLOCKS) * 1024 + tid, nconv * 1024);
        return;
    }
    int g = blockIdx.x / NWG;
    int w = blockIdx.x % NWG;
    int half = (N + 1) / 2;
    for (int i = tid; i < half; i += 1024) cnt[i] = 0;
    __syncthreads();

    int C = (E + NWG - 1) / NWG;
    int lo = w * C, hi = min(lo + C, E);
    if (g < 5) {
        const int* arr = dst_all + (size_t)g * E;
        for (int e = lo + tid; e < hi; e += 1024) {
            int d = __builtin_nontemporal_load(&arr[e]);
            unsigned int sh = (d & 1) * 16;
            unsigned int old = atomicAdd(&cnt[d >> 1], 1u << sh);
            rank_local[(size_t)g * E + e] = (unsigned short)((old >> sh) & 0xffffu);
        }
    } else {
        const int* arr = src_all + (size_t)(g - 5) * E;
        for (int e = lo + tid; e < hi; e += 1024) {
            int d = __builtin_nontemporal_load(&arr[e]);
            atomicAdd(&cnt[d >> 1], 1u << ((d & 1) * 16));
        }
    }
    __syncthreads();
    unsigned short* outp = partial + ((size_t)g * NWG + w) * N;
    for (int n = tid; n < N; n += 1024)
        outp[n] = (unsigned short)((cnt[n >> 1] >> ((n & 1) * 16)) & 0xffffu);
}

// ---------------- reduce partials -> degrees/rsqrt; in-place exclusive prefix over chunks ----------------
__global__ void reduce_kernel(unsigned short* __restrict__ partial, int* __restrict__ cnt_dst,
                              float* __restrict__ rsq_out, float* __restrict__ rsq_in, int N) {
    int i = blockIdx.x * blockDim.x + threadIdx.x;
    int stride = gridDim.x * blockDim.x;
    int tot = 10 * N;
    for (; i < tot; i += stride) {
        int g = i / N, n = i - g * N;
        unsigned short* p = partial + ((size_t)g * NWG) * N + n;
        int sum = 0;
        #pragma unroll
        for (int w = 0; w < NWG; ++w) {
            int v = p[(size_t)w * N];
            p[(size_t)w * N] = (unsigned short)sum;   // exclusive prefix (rank base per chunk)
            sum += v;
        }
        float r = rsqrtf((float)max(sum, 1));
        if (g < 5) { cnt_dst[i] = sum; rsq_in[i] = r; }
        else rsq_out[i - 5 * N] = r;
    }
}

// 5 blocks, one per etype
__global__ __launch_bounds__(1024) void scan_kernel(const int* __restrict__ cnt_all,
                                                    int* __restrict__ off_all, int n) {
    const int* cnt = cnt_all + (size_t)blockIdx.x * n;
    int* off = off_all + (size_t)blockIdx.x * (n + 1);
    __shared__ int ssum[1024];
    int t = threadIdx.x;
    int chunk = (n + 1023) / 1024;
    int lo = t * chunk, hi = min(lo + chunk, n);
    int s = 0;
    for (int i = lo; i < hi; ++i) s += cnt[i];
    ssum[t] = s;
    __syncthreads();
    for (int d = 1; d < 1024; d <<= 1) {
        int v = (t >= d) ? ssum[t - d] : 0;
        __syncthreads();
        ssum[t] += v;
        __syncthreads();
    }
    int excl = (t == 0) ? 0 : ssum[t - 1];
    for (int i = lo; i < hi; ++i) { off[i] = excl; excl += cnt[i]; }
    if (t == 1023) off[n] = ssum[1023];
}

// ---------------- atomic-free permutation: 4-edge ILP batches, nontemporal scatter ----------------
__global__ __launch_bounds__(256) void permute_kernel(
    const int* __restrict__ src_all, const int* __restrict__ dst_all,
    const int* __restrict__ off, const unsigned short* __restrict__ partial,
    const unsigned short* __restrict__ rank_local,
    unsigned short* __restrict__ sorted, int E, int N)
{
    int gid = blockIdx.x * blockDim.x + threadIdx.x;
    int nthr = gridDim.x * blockDim.x;
    int tot = 5 * E;                    // divisible by 4
    int C = (E + NWG - 1) / NWG;
    for (int i0 = gid * 4; i0 < tot; i0 += nthr * 4) {
        int d[4], s[4], rl[4];
        #pragma unroll
        for (int j = 0; j < 4; ++j) {
            d[j]  = __builtin_nontemporal_load(&dst_all[i0 + j]);
            s[j]  = __builtin_nontemporal_load(&src_all[i0 + j]);
            rl[j] = __builtin_nontemporal_load(&rank_local[i0 + j]);
        }
        int pos[4];
        #pragma unroll
        for (int j = 0; j < 4; ++j) {
            int i = i0 + j;
            int k = i / E, e = i - k * E;
            int w = e / C;
            pos[j] = off[(size_t)k * (N + 1) + d[j]]
                   + partial[((size_t)k * NWG + w) * N + d[j]]
                   + rl[j] + k * E;
        }
        #pragma unroll
        for (int j = 0; j < 4; ++j)
            __builtin_nontemporal_store((unsigned short)s[j], &sorted[pos[j]]);
    }
}

// ---------------- feat convert (standalone, fallback path) ----------------
__global__ void convert_kernel(const float* __restrict__ f0, const float* __restrict__ f1,
                               const float* __restrict__ f2, const float* __restrict__ f3,
                               unsigned int* __restrict__ featB, float* __restrict__ alast, int N) {
    convert_body(f0, f1, f2, f3, featB, alast, N,
                 blockIdx.x * blockDim.x + threadIdx.x, gridDim.x * blockDim.x);
}

// ---------------- weight prep: transpose + bf16, combined biases ----------------
__global__ void prep_weights_kernel(const float* __restrict__ Wp,
                                    const float* __restrict__ Wc1, const float* __restrict__ Wc2,
                                    const float* __restrict__ bc1, const float* __restrict__ bc2,
                                    unsigned short* __restrict__ WpT,
                                    unsigned short* __restrict__ WcT,
                                    float* __restrict__ cbias) {
    int i = blockIdx.x * blockDim.x + threadIdx.x;
    int stride = gridDim.x * blockDim.x;
    const int nWp = 4 * 128 * 384;
    for (int p = i; p < nWp; p += stride) {
        int t = p / (128 * 384), rem = p % (128 * 384);
        int c = rem / 384, k = rem % 384;
        WpT[p] = f2b(Wp[(size_t)t * INF * HD + (size_t)k * HD + c]);
    }
    const int nWc = 5 * 128 * 128;
    for (int p = i; p < 2 * nWc; p += stride) {
        int layer = p / nWc, rem = p % nWc;
        int e = rem / (128 * 128), rem2 = rem % (128 * 128);
        int c = rem2 / 128, k = rem2 % 128;
        const float* W = layer ? Wc2 : Wc1;
        WcT[p] = f2b(W[(size_t)e * 128 * 128 + (size_t)k * 128 + c]);
    }
    // cbias[layer][t][c]: t0<-bc[4], t1<-bc[0], t2<-bc[2]+bc[3], t3<-bc[1]
    for (int p = i; p < 2 * 4 * 128; p += stride) {
        int layer = p / 512, rem = p % 512;
        int t = rem / 128, c = rem % 128;
        const float* bc = layer ? bc2 : bc1;
        float v;
        if (t == 0) v = bc[4 * 128 + c];
        else if (t == 1) v = bc[0 * 128 + c];
        else if (t == 2) v = bc[2 * 128 + c] + bc[3 * 128 + c];
        else v = bc[1 * 128 + c];
        cbias[p] = v;
    }
}

// ---------------- batched MFMA GEMM (bf16 A), optional rank-1 / bias / rowscale ----------------
struct GemmDesc {
    const unsigned short* A;      // [M][lda] bf16, rows 16B-aligned
    const unsigned short* Bt;     // [128][K] bf16
    const float* bias;            // [128] or null
    const float* rowscale;        // [M] or null
    const float* alast;           // [M] or null (rank-1 left vector)
    const float* wlast;           // [128] or null (rank-1 right vector)
    unsigned short* out;          // [M][128] bf16
};
struct GemmBatch { GemmDesc d[5]; };

__global__ __launch_bounds__(256) void gemm_mfma_kernel(
    GemmBatch batch, int lda, int M, int K, int relu)
{
    const GemmDesc dsc = batch.d[blockIdx.y];
    const unsigned short* __restrict__ Bt = dsc.Bt;
    const unsigned short* __restrict__ A = dsc.A;

    __shared__ __align__(16) unsigned short As[64][72];   // +8 pad: 144B row stride
    __shared__ __align__(16) unsigned short Bs[128][72];
    const int tid = threadIdx.x;
    const int bm = blockIdx.x * 64;
    const int wid = tid >> 6, lane = tid & 63;
    const int wr = wid & 1, wc = wid >> 1;      // 2x2 wave grid: 32 rows x 64 cols each
    const int l15 = lane & 15, l4 = lane >> 4;

    f32x4 acc[2][4] = {};

    for (int k0 = 0; k0 < K; k0 += 64) {
        {
            int r = tid >> 2, q = tid & 3;      // 16 bf16 per thread, vectorized
            int gm = bm + r;
            if (gm < M) {
                const uint4* g = (const uint4*)(A + (size_t)gm * lda + k0 + q * 16);
                *(uint4*)&As[r][q * 16] = g[0];
                *(uint4*)&As[r][q * 16 + 8] = g[1];
            } else {
                uint4 z = {0, 0, 0, 0};
                *(uint4*)&As[r][q * 16] = z;
                *(uint4*)&As[r][q * 16 + 8] = z;
            }
        }
        {
            int col = tid >> 1, hf = tid & 1;   // 32 bf16 per thread from Bt[col][k0+hf*32..]
            const uint4* g = (const uint4*)(Bt + (size_t)col * K + k0 + hf * 32);
            #pragma unroll
            for (int j = 0; j < 4; ++j)
                *(uint4*)&Bs[col][hf * 32 + j * 8] = g[j];
        }
        __syncthreads();
        #pragma unroll
        for (int kk = 0; kk < 2; ++kk) {
            short8 a[2], b[4];
            #pragma unroll
            for (int mi = 0; mi < 2; ++mi)
                a[mi] = *(const short8*)&As[wr * 32 + mi * 16 + l15][kk * 32 + l4 * 8];
            #pragma unroll
            for (int ni = 0; ni < 4; ++ni)
                b[ni] = *(const short8*)&Bs[wc * 64 + ni * 16 + l15][kk * 32 + l4 * 8];
            #pragma unroll
            for (int mi = 0; mi < 2; ++mi)
                #pragma unroll
                for (int ni = 0; ni < 4; ++ni)
                    acc[mi][ni] = __builtin_amdgcn_mfma_f32_16x16x32_bf16(
                        a[mi], b[ni], acc[mi][ni], 0, 0, 0);
        }
        __syncthreads();
    }

    // epilogue: C/D layout col=lane&15, row=(lane>>4)*4+reg  [m89-verified]
    #pragma unroll
    for (int mi = 0; mi < 2; ++mi) {
        #pragma unroll
        for (int r = 0; r < 4; ++r) {
            int grow = bm + wr * 32 + mi * 16 + l4 * 4 + r;
            if (grow >= M) continue;
            float rs = dsc.rowscale ? dsc.rowscale[grow] : 1.f;
            float al = dsc.alast ? dsc.alast[grow] : 0.f;
            #pragma unroll
            for (int ni = 0; ni < 4; ++ni) {
                int gcol = wc * 64 + ni * 16 + l15;
                float v = acc[mi][ni][r];
                if (dsc.wlast) v += al * dsc.wlast[gcol];
                if (dsc.bias) v += dsc.bias[gcol];
                v *= rs;
                if (relu) v = fmaxf(v, 0.f);
                dsc.out[(size_t)grow * HD + gcol] = f2b(v);
            }
        }
    }
}

// ---------------- batched CSR gather: wide loads ----------------
// Wave = 4 x 16-lane groups; group `sub` handles edges e+r*4+sub, each lane loads
// uint4 (8 bf16 channels l16*8..+8). Cross-sub combine via shfl_xor(16|32).
struct GatherDesc {
    const unsigned short* msgA; const unsigned short* sortedA;
    const int* offA; const float* rsqA;
    const unsigned short* msgB; const unsigned short* sortedB;  // null if single
    const int* offB; const float* rsqB;
    const float* bias; void* out;
};
struct GatherBatch { GatherDesc d[4]; };

__device__ __forceinline__ void accum8(uint4 v, float* acc) {
    acc[0] += b2f(v.x & 0xffffu); acc[1] += b2f(v.x >> 16);
    acc[2] += b2f(v.y & 0xffffu); acc[3] += b2f(v.y >> 16);
    acc[4] += b2f(v.z & 0xffffu); acc[5] += b2f(v.z >> 16);
    acc[6] += b2f(v.w & 0xffffu); acc[7] += b2f(v.w >> 16);
}

__device__ __forceinline__ void gather_seg(
    const unsigned short* __restrict__ msg, const unsigned short* __restrict__ sorted,
    int beg, int end, int sub, int lbyte, float* acc)
{
    const char* mbase = (const char*)msg;
    int e = beg;
    for (; e + 16 <= end; e += 16) {            // full chunks: 16 edges, 4 loads/lane
        uint4 v[4];
        #pragma unroll
        for (int r = 0; r < 4; ++r) {
            int s = sorted[e + r * 4 + sub];
            v[r] = *(const uint4*)(mbase + (size_t)s * 256 + lbyte);
        }
        #pragma unroll
        for (int r = 0; r < 4; ++r) accum8(v[r], acc);
    }
    if (e < end) {                               // masked tail chunk
        #pragma unroll
        for (int r = 0; r < 4; ++r) {
            int idx = e + r * 4 + sub;
            if (idx < end) {
                int s = sorted[idx];
                uint4 v = *(const uint4*)(mbase + (size_t)s * 256 + lbyte);
                accum8(v, acc);
            }
        }
    }
}

template<int OUT_BF16>
__global__ __launch_bounds__(256) void gather_kernel(GatherBatch batch, int n)
{
    const GatherDesc d = batch.d[blockIdx.y];
    int node = blockIdx.x * 4 + (threadIdx.x >> 6);   // wave-uniform
    if (node >= n) return;
    int lane = threadIdx.x & 63;
    int sub = lane >> 4;
    int l16 = lane & 15;
    int lbyte = l16 * 16;

    float comb[8];
    {
        float acc[8] = {};
        gather_seg(d.msgA, d.sortedA, d.offA[node], d.offA[node + 1], sub, lbyte, acc);
        float rA = d.rsqA[node];
        if (d.msgB) {
            float acc2[8] = {};
            gather_seg(d.msgB, d.sortedB, d.offB[node], d.offB[node + 1], sub, lbyte, acc2);
            float rB = d.rsqB[node];
            #pragma unroll
            for (int c = 0; c < 8; ++c) comb[c] = acc[c] * rA + acc2[c] * rB;
        } else {
            #pragma unroll
            for (int c = 0; c < 8; ++c) comb[c] = acc[c] * rA;
        }
    }
    #pragma unroll
    for (int c = 0; c < 8; ++c) {
        comb[c] += __shfl_xor(comb[c], 16);
        comb[c] += __shfl_xor(comb[c], 32);
    }
    if (sub == 0) {
        const float* bptr = d.bias + l16 * 8;
        float4 b0 = *(const float4*)bptr;
        float4 b1 = *(const float4*)(bptr + 4);
        float o[8] = {comb[0] + b0.x, comb[1] + b0.y, comb[2] + b0.z, comb[3] + b0.w,
                      comb[4] + b1.x, comb[5] + b1.y, comb[6] + b1.z, comb[7] + b1.w};
        #pragma unroll
        for (int c = 0; c < 8; ++c) o[c] = fmaxf(o[c], 0.f);
        if (OUT_BF16) {
            uint4 pv;
            pv.x = ((unsigned int)f2b(o[1]) << 16) | f2b(o[0]);
            pv.y = ((unsigned int)f2b(o[3]) << 16) | f2b(o[2]);
            pv.z = ((unsigned int)f2b(o[5]) << 16) | f2b(o[4]);
            pv.w = ((unsigned int)f2b(o[7]) << 16) | f2b(o[6]);
            *(uint4*)((char*)d.out + (size_t)node * 256 + lbyte) = pv;
        } else {
            float4 f0 = {o[0], o[1], o[2], o[3]};
            float4 f1 = {o[4], o[5], o[6], o[7]};
            float4* op = (float4*)((char*)d.out + (size_t)node * 512 + (size_t)l16 * 32);
            op[0] = f0; op[1] = f1;
        }
    }
}

extern "C" void kernel_launch(void* const* d_in, const int* in_sizes, int n_in,
                              void* d_out, int out_size, void* d_ws, size_t ws_size,
                              hipStream_t stream)
{
    const float* feat[4] = {(const float*)d_in[0], (const float*)d_in[1],
                            (const float*)d_in[2], (const float*)d_in[3]};
    const int* src_all = (const int*)d_in[4];
    const int* dst_all = (const int*)d_in[5];
    const float* Wp  = (const float*)d_in[6];
    const float* bp  = (const float*)d_in[7];
    const float* Wc1 = (const float*)d_in[8];
    const float* bc1 = (const float*)d_in[9];
    const float* Wc2 = (const float*)d_in[10];
    const float* bc2 = (const float*)d_in[11];

    const int N = in_sizes[0] / INF;      // 50000  (< 65536: ushort ids)
    const int E = in_sizes[4] / 5;        // 1,600,000

    // etypes: k -> (src_type, dst_type): (0,1) (1,3) (3,2) (0,2) (2,0)
    const int st_[5] = {0, 1, 3, 0, 2};

    // ---- workspace layout (256B-aligned) ----
    char* w = (char*)d_ws;
    auto take = [&](size_t bytes) { char* p = w; w += (bytes + 255) & ~(size_t)255; return p; };
    int*   cnt_dst = (int*)take(5 * (size_t)N * 4);
    float* rsq_out = (float*)take(5 * (size_t)N * 4);
    float* rsq_in  = (float*)take(5 * (size_t)N * 4);
    int*   off     = (int*)take(5 * (size_t)(N + 1) * 4);
    unsigned short* sorted = (unsigned short*)take(5 * (size_t)E * 2);  // 16 MB, live whole pass
    float* alast   = (float*)take(4 * (size_t)N * 4);
    unsigned short* WpT = (unsigned short*)take(4 * 128 * 384 * 2);
    unsigned short* WcT = (unsigned short*)take(2 * 5 * 128 * 128 * 2);
    float* cbias   = (float*)take(2 * 4 * 128 * 4);

    const size_t pr_bytes = 10u * NWG * (size_t)N * 2 + 5 * (size_t)E * 2;  // partial+rank (32MB)
    const size_t blob_sz = 4 * (size_t)N * 384 * 2;                         // featB (153.6MB)
    size_t fixed_used = (size_t)(w - (char*)d_ws);
    bool roomy = ws_size >= fixed_used + pr_bytes + blob_sz + (1u << 20);

    unsigned short *partial, *rank_local, *featB, *msg;
    if (roomy) {
        partial    = (unsigned short*)take(10u * NWG * (size_t)N * 2);
        rank_local = (unsigned short*)take(5 * (size_t)E * 2);
        char* blob = (char*)take(blob_sz);
        featB = (unsigned short*)blob;
        msg   = (unsigned short*)blob;   // overlays featB after proj
    } else {
        char* blob = (char*)take(blob_sz);
        partial    = (unsigned short*)blob;
        rank_local = (unsigned short*)(blob + 10u * NWG * (size_t)N * 2);
        featB      = (unsigned short*)blob;
        msg        = (unsigned short*)(blob + 32u * 1024 * 1024);
    }
    // h0 in d_out lower half (bf16), h1 in d_out upper half (bf16); both dead
    // before layer-2 gathers write f32 over the full d_out.
    unsigned short* h0 = (unsigned short*)d_out;
    unsigned short* h1 = (unsigned short*)d_out + 4 * (size_t)N * HD;

    const int gblk = (N + 63) / 64;

    prep_weights_kernel<<<512, 256, 0, stream>>>(Wp, Wc1, Wc2, bc1, bc2, WpT, WcT, cbias);

    // hist (160 blocks) || convert (512 blocks if roomy) in one dispatch
    hist_conv_kernel<<<roomy ? HIST_BLOCKS + 512 : HIST_BLOCKS, 1024, 0, stream>>>(
        src_all, dst_all, partial, rank_local, E, N,
        feat[0], feat[1], feat[2], feat[3], (unsigned int*)featB, alast);
    reduce_kernel<<<(10 * N + 255) / 256, 256, 0, stream>>>(partial, cnt_dst, rsq_out, rsq_in, N);
    scan_kernel<<<5, 1024, 0, stream>>>(cnt_dst, off, N);
    permute_kernel<<<2048, 256, 0, stream>>>(src_all, dst_all, off, partial, rank_local,
                                             sorted, E, N);
    if (!roomy)
        convert_kernel<<<2048, 256, 0, stream>>>(feat[0], feat[1], feat[2], feat[3],
                                                 (unsigned int*)featB, alast, N);

    // ---- input projections (batched over 4 types) ----
    {
        GemmBatch pb = {};
        for (int t = 0; t < 4; ++t) {
            pb.d[t].A = featB + (size_t)t * N * 384;
            pb.d[t].Bt = WpT + (size_t)t * 128 * 384;
            pb.d[t].bias = bp + (size_t)t * HD;
            pb.d[t].rowscale = nullptr;
            pb.d[t].alast = alast + (size_t)t * N;
            pb.d[t].wlast = Wp + (size_t)t * INF * HD + 384 * HD;
            pb.d[t].out = h0 + (size_t)t * N * HD;
        }
        gemm_mfma_kernel<<<dim3(gblk, 4), 256, 0, stream>>>(pb, 384, N, 384, 1);
    }

    // ---- 2 hetero conv layers ----
    for (int layer = 0; layer < 2; ++layer) {
        const unsigned short* hin = layer ? h1 : h0;
        const unsigned short* WT = WcT + (size_t)layer * 5 * 128 * 128;
        const float* cb = cbias + (size_t)layer * 4 * 128;

        // 5 independent conv GEMMs in one dispatch
        {
            GemmBatch cbch = {};
            for (int k = 0; k < 5; ++k) {
                cbch.d[k].A = hin + (size_t)st_[k] * N * HD;
                cbch.d[k].Bt = WT + (size_t)k * 128 * 128;
                cbch.d[k].bias = nullptr;
                cbch.d[k].rowscale = rsq_out + (size_t)k * N;
                cbch.d[k].alast = nullptr;
                cbch.d[k].wlast = nullptr;
                cbch.d[k].out = msg + (size_t)k * N * HD;
            }
            gemm_mfma_kernel<<<dim3(gblk, 5), 256, 0, stream>>>(cbch, HD, N, 128, 0);
        }

        // 4 gathers (k2+k3 dual into t2) in one dispatch
        {
            auto S = [&](int k) { return sorted + (size_t)k * E; };
            auto O = [&](int k) { return off + (size_t)k * (N + 1); };
            auto R = [&](int k) { return rsq_in + (size_t)k * N; };
            auto M_ = [&](int k) { return msg + (size_t)k * N * HD; };
            const int ksA[4] = {0, 1, 2, 4};
            const int dt [4] = {1, 3, 2, 0};
            GatherBatch gb = {};
            for (int y = 0; y < 4; ++y) {
                int k = ksA[y];
                gb.d[y].msgA = M_(k); gb.d[y].sortedA = S(k);
                gb.d[y].offA = O(k);  gb.d[y].rsqA = R(k);
                gb.d[y].msgB = nullptr; gb.d[y].sortedB = nullptr;
                gb.d[y].offB = nullptr; gb.d[y].rsqB = nullptr;
                gb.d[y].bias = cb + (size_t)dt[y] * HD;
                if (layer == 0)
                    gb.d[y].out = h1 + (size_t)dt[y] * N * HD;
                else
                    gb.d[y].out = (float*)d_out + (size_t)dt[y] * N * HD;
            }
            gb.d[2].msgB = M_(3); gb.d[2].sortedB = S(3);
            gb.d[2].offB = O(3);  gb.d[2].rsqB = R(3);
            const int gg = (N + 3) / 4;
            if (layer == 0)
                gather_kernel<1><<<dim3(gg, 4), 256, 0, stream>>>(gb, N);
            else
                gather_kernel<0><<<dim3(gg, 4), 256, 0, stream>>>(gb, N);
        }
    }
}

// Round 12
// 1016.600 us; speedup vs baseline: 1.1323x; 1.0937x over previous
//
#include <hip/hip_runtime.h>
#include <hip/hip_bf16.h>

#define INF 385
#define HD 128
#define NWG 16   // workgroups per histogram group
#define HIST_BLOCKS (10 * NWG)
#define NBUCKET 64
#define BK_CHUNK 8192

typedef __attribute__((ext_vector_type(8))) short short8;
typedef __attribute__((ext_vector_type(4))) float f32x4;

__device__ inline unsigned short f2b(float f) {
    __hip_bfloat16 h = __float2bfloat16(f);
    return *reinterpret_cast<unsigned short*>(&h);
}
__device__ inline float b2f(unsigned int lo16) {
    union { unsigned int u; float f; } c; c.u = lo16 << 16; return c.f;
}

// ---------------- convert body: feat f32 [N][385] -> bf16 [N][384] + alast ----------------
__device__ __forceinline__ void convert_body(
    const float* f0, const float* f1, const float* f2, const float* f3,
    unsigned int* featB, float* alast, int N, int gid, int nthr)
{
    int per = N * 192;
    int tot = 4 * per;
    for (int p = gid; p < tot; p += nthr) {
        int t = p / per, rem = p - t * per;
        int n = rem / 192, c2 = (rem - n * 192) * 2;
        const float* f = (t < 2) ? (t == 0 ? f0 : f1) : (t == 2 ? f2 : f3);
        const float* row = f + (size_t)n * INF;
        float a = row[c2], b = row[c2 + 1];
        featB[p] = ((unsigned int)f2b(b) << 16) | f2b(a);
    }
    for (int p = gid; p < 4 * N; p += nthr) {
        int t = p / N, n = p - t * N;
        const float* f = (t < 2) ? (t == 0 ? f0 : f1) : (t == 2 ? f2 : f3);
        alast[p] = f[(size_t)n * INF + 384];
    }
}

// ---------------- fused: LDS-privatized histogram (blocks<HIST_BLOCKS) + convert ----------------
__global__ __launch_bounds__(1024) void hist_conv_kernel(
    const int* __restrict__ src_all, const int* __restrict__ dst_all,
    unsigned short* __restrict__ partial,    // [10][NWG][N]
    unsigned short* __restrict__ rank_local, // [5][E]
    int E, int N,
    const float* __restrict__ f0, const float* __restrict__ f1,
    const float* __restrict__ f2, const float* __restrict__ f3,
    unsigned int* __restrict__ featB, float* __restrict__ alast)
{
    __shared__ unsigned int cnt[25000];      // 2 packed ushort counters per uint
    int tid = threadIdx.x;
    if (blockIdx.x >= HIST_BLOCKS) {
        int nconv = gridDim.x - HIST_BLOCKS;
        convert_body(f0, f1, f2, f3, featB, alast, N,
                     (blockIdx.x - HIST_BLOCKS) * 1024 + tid, nconv * 1024);
        return;
    }
    int g = blockIdx.x / NWG;
    int w = blockIdx.x % NWG;
    int half = (N + 1) / 2;
    for (int i = tid; i < half; i += 1024) cnt[i] = 0;
    __syncthreads();

    int C = (E + NWG - 1) / NWG;
    int lo = w * C, hi = min(lo + C, E);
    if (g < 5) {
        const int* arr = dst_all + (size_t)g * E;
        for (int e = lo + tid; e < hi; e += 1024) {
            int d = __builtin_nontemporal_load(&arr[e]);
            unsigned int sh = (d & 1) * 16;
            unsigned int old = atomicAdd(&cnt[d >> 1], 1u << sh);
            rank_local[(size_t)g * E + e] = (unsigned short)((old >> sh) & 0xffffu);
        }
    } else {
        const int* arr = src_all + (size_t)(g - 5) * E;
        for (int e = lo + tid; e < hi; e += 1024) {
            int d = __builtin_nontemporal_load(&arr[e]);
            atomicAdd(&cnt[d >> 1], 1u << ((d & 1) * 16));
        }
    }
    __syncthreads();
    unsigned short* outp = partial + ((size_t)g * NWG + w) * N;
    for (int n = tid; n < N; n += 1024)
        outp[n] = (unsigned short)((cnt[n >> 1] >> ((n & 1) * 16)) & 0xffffu);
}

// ---------------- reduce partials -> degrees/rsqrt; in-place exclusive prefix over chunks ----------------
__global__ void reduce_kernel(unsigned short* __restrict__ partial, int* __restrict__ cnt_dst,
                              float* __restrict__ rsq_out, float* __restrict__ rsq_in, int N) {
    int i = blockIdx.x * blockDim.x + threadIdx.x;
    int stride = gridDim.x * blockDim.x;
    int tot = 10 * N;
    for (; i < tot; i += stride) {
        int g = i / N, n = i - g * N;
        unsigned short* p = partial + ((size_t)g * NWG) * N + n;
        int sum = 0;
        #pragma unroll
        for (int w = 0; w < NWG; ++w) {
            int v = p[(size_t)w * N];
            p[(size_t)w * N] = (unsigned short)sum;   // exclusive prefix (rank base per chunk)
            sum += v;
        }
        float r = rsqrtf((float)max(sum, 1));
        if (g < 5) { cnt_dst[i] = sum; rsq_in[i] = r; }
        else rsq_out[i - 5 * N] = r;
    }
}

// 5 blocks, one per etype
__global__ __launch_bounds__(1024) void scan_kernel(const int* __restrict__ cnt_all,
                                                    int* __restrict__ off_all, int n) {
    const int* cnt = cnt_all + (size_t)blockIdx.x * n;
    int* off = off_all + (size_t)blockIdx.x * (n + 1);
    __shared__ int ssum[1024];
    int t = threadIdx.x;
    int chunk = (n + 1023) / 1024;
    int lo = t * chunk, hi = min(lo + chunk, n);
    int s = 0;
    for (int i = lo; i < hi; ++i) s += cnt[i];
    ssum[t] = s;
    __syncthreads();
    for (int d = 1; d < 1024; d <<= 1) {
        int v = (t >= d) ? ssum[t - d] : 0;
        __syncthreads();
        ssum[t] += v;
        __syncthreads();
    }
    int excl = (t == 0) ? 0 : ssum[t - 1];
    for (int i = lo; i < hi; ++i) { off[i] = excl; excl += cnt[i]; }
    if (t == 1023) off[n] = ssum[1023];
}

// ---------------- pass 1: bin edges by position-space bucket (exactly W per bucket) ----------------
__global__ __launch_bounds__(1024) void bin_kernel(
    const int* __restrict__ src_all, const int* __restrict__ dst_all,
    const int* __restrict__ off, const unsigned short* __restrict__ partial,
    const unsigned short* __restrict__ rank_local,
    int* __restrict__ cursor,              // [5][NBUCKET], zeroed
    unsigned int* __restrict__ staging,    // [5][NBUCKET][W] (src<<16 | pos_local)
    int E, int N, int W, int wgPerEt)
{
    __shared__ int pos_s[BK_CHUNK];
    __shared__ unsigned short src_s[BK_CHUNK];
    __shared__ int cntb[NBUCKET], gbase[NBUCKET], lcur[NBUCKET];
    int k = blockIdx.x / wgPerEt;
    int wg = blockIdx.x % wgPerEt;
    int tid = threadIdx.x;
    int lo = wg * BK_CHUNK, hi = min(lo + BK_CHUNK, E);
    if (lo >= E) return;
    if (tid < NBUCKET) cntb[tid] = 0;
    __syncthreads();

    int C = (E + NWG - 1) / NWG;
    const int* srcs = src_all + (size_t)k * E;
    const int* dsts = dst_all + (size_t)k * E;
    const unsigned short* rl = rank_local + (size_t)k * E;
    const int* offk = off + (size_t)k * (N + 1);
    const unsigned short* pk = partial + (size_t)k * NWG * N;

    #pragma unroll
    for (int j = 0; j < BK_CHUNK / 1024; ++j) {
        int idx = tid + j * 1024;
        int e = lo + idx;
        if (e < hi) {
            int d = __builtin_nontemporal_load(&dsts[e]);
            int s = __builtin_nontemporal_load(&srcs[e]);
            int r = __builtin_nontemporal_load(&rl[e]);
            int w = e / C;
            int pos = offk[d] + pk[(size_t)w * N + d] + r;
            pos_s[idx] = pos;
            src_s[idx] = (unsigned short)s;
            atomicAdd(&cntb[pos / W], 1);
        }
    }
    __syncthreads();
    if (tid < NBUCKET) {
        gbase[tid] = atomicAdd(&cursor[k * NBUCKET + tid], cntb[tid]);
        lcur[tid] = 0;
    }
    __syncthreads();
    int cnt = hi - lo;
    #pragma unroll
    for (int j = 0; j < BK_CHUNK / 1024; ++j) {
        int idx = tid + j * 1024;
        if (idx < cnt) {
            int pos = pos_s[idx];
            int b = pos / W;
            int l = atomicAdd(&lcur[b], 1);
            unsigned int pair = ((unsigned int)src_s[idx] << 16) | (unsigned int)(pos - b * W);
            staging[((size_t)k * NBUCKET + b) * W + gbase[b] + l] = pair;
        }
    }
}

// ---------------- pass 2: per-(etype,bucket) scatter into a 50KB hot window ----------------
__global__ __launch_bounds__(256) void unbucket_kernel(
    const unsigned int* __restrict__ staging, const int* __restrict__ cursor,
    unsigned short* __restrict__ sorted, int E, int W)
{
    int k = blockIdx.x / NBUCKET;
    int b = blockIdx.x % NBUCKET;
    int cnt = cursor[k * NBUCKET + b];
    const unsigned int* stg = staging + ((size_t)k * NBUCKET + b) * W;
    unsigned short* out = sorted + (size_t)k * E + (size_t)b * W;
    int i = threadIdx.x;
    for (; i + 768 < cnt; i += 1024) {
        unsigned int p0 = stg[i], p1 = stg[i + 256], p2 = stg[i + 512], p3 = stg[i + 768];
        out[p0 & 0xffffu] = (unsigned short)(p0 >> 16);
        out[p1 & 0xffffu] = (unsigned short)(p1 >> 16);
        out[p2 & 0xffffu] = (unsigned short)(p2 >> 16);
        out[p3 & 0xffffu] = (unsigned short)(p3 >> 16);
    }
    for (; i < cnt; i += 256) {
        unsigned int p0 = stg[i];
        out[p0 & 0xffffu] = (unsigned short)(p0 >> 16);
    }
}

// ---------------- single-pass permute (fallback when ws too small for staging) ----------------
__global__ __launch_bounds__(256) void permute_kernel(
    const int* __restrict__ src_all, const int* __restrict__ dst_all,
    const int* __restrict__ off, const unsigned short* __restrict__ partial,
    const unsigned short* __restrict__ rank_local,
    unsigned short* __restrict__ sorted, int E, int N)
{
    int gid = blockIdx.x * blockDim.x + threadIdx.x;
    int nthr = gridDim.x * blockDim.x;
    int tot = 5 * E;
    int C = (E + NWG - 1) / NWG;
    for (int i0 = gid * 4; i0 < tot; i0 += nthr * 4) {
        int d[4], s[4], rl[4];
        #pragma unroll
        for (int j = 0; j < 4; ++j) {
            d[j]  = __builtin_nontemporal_load(&dst_all[i0 + j]);
            s[j]  = __builtin_nontemporal_load(&src_all[i0 + j]);
            rl[j] = __builtin_nontemporal_load(&rank_local[i0 + j]);
        }
        #pragma unroll
        for (int j = 0; j < 4; ++j) {
            int i = i0 + j;
            int k = i / E, e = i - k * E;
            int w = e / C;
            int pos = off[(size_t)k * (N + 1) + d[j]]
                    + partial[((size_t)k * NWG + w) * N + d[j]]
                    + rl[j] + k * E;
            __builtin_nontemporal_store((unsigned short)s[j], &sorted[pos]);
        }
    }
}

// ---------------- feat convert (standalone, fallback path) ----------------
__global__ void convert_kernel(const float* __restrict__ f0, const float* __restrict__ f1,
                               const float* __restrict__ f2, const float* __restrict__ f3,
                               unsigned int* __restrict__ featB, float* __restrict__ alast, int N) {
    convert_body(f0, f1, f2, f3, featB, alast, N,
                 blockIdx.x * blockDim.x + threadIdx.x, gridDim.x * blockDim.x);
}

// ---------------- weight prep: transpose + bf16, combined biases ----------------
__global__ void prep_weights_kernel(const float* __restrict__ Wp,
                                    const float* __restrict__ Wc1, const float* __restrict__ Wc2,
                                    const float* __restrict__ bc1, const float* __restrict__ bc2,
                                    unsigned short* __restrict__ WpT,
                                    unsigned short* __restrict__ WcT,
                                    float* __restrict__ cbias) {
    int i = blockIdx.x * blockDim.x + threadIdx.x;
    int stride = gridDim.x * blockDim.x;
    const int nWp = 4 * 128 * 384;
    for (int p = i; p < nWp; p += stride) {
        int t = p / (128 * 384), rem = p % (128 * 384);
        int c = rem / 384, k = rem % 384;
        WpT[p] = f2b(Wp[(size_t)t * INF * HD + (size_t)k * HD + c]);
    }
    const int nWc = 5 * 128 * 128;
    for (int p = i; p < 2 * nWc; p += stride) {
        int layer = p / nWc, rem = p % nWc;
        int e = rem / (128 * 128), rem2 = rem % (128 * 128);
        int c = rem2 / 128, k = rem2 % 128;
        const float* W = layer ? Wc2 : Wc1;
        WcT[p] = f2b(W[(size_t)e * 128 * 128 + (size_t)k * 128 + c]);
    }
    // cbias[layer][t][c]: t0<-bc[4], t1<-bc[0], t2<-bc[2]+bc[3], t3<-bc[1]
    for (int p = i; p < 2 * 4 * 128; p += stride) {
        int layer = p / 512, rem = p % 512;
        int t = rem / 128, c = rem % 128;
        const float* bc = layer ? bc2 : bc1;
        float v;
        if (t == 0) v = bc[4 * 128 + c];
        else if (t == 1) v = bc[0 * 128 + c];
        else if (t == 2) v = bc[2 * 128 + c] + bc[3 * 128 + c];
        else v = bc[1 * 128 + c];
        cbias[p] = v;
    }
}

// ---------------- batched MFMA GEMM (bf16 A), optional rank-1 / bias / rowscale ----------------
struct GemmDesc {
    const unsigned short* A;      // [M][lda] bf16, rows 16B-aligned
    const unsigned short* Bt;     // [128][K] bf16
    const float* bias;            // [128] or null
    const float* rowscale;        // [M] or null
    const float* alast;           // [M] or null (rank-1 left vector)
    const float* wlast;           // [128] or null (rank-1 right vector)
    unsigned short* out;          // [M][128] bf16
};
struct GemmBatch { GemmDesc d[5]; };

__global__ __launch_bounds__(256) void gemm_mfma_kernel(
    GemmBatch batch, int lda, int M, int K, int relu)
{
    const GemmDesc dsc = batch.d[blockIdx.y];
    const unsigned short* __restrict__ Bt = dsc.Bt;
    const unsigned short* __restrict__ A = dsc.A;

    __shared__ __align__(16) unsigned short As[64][72];   // +8 pad: 144B row stride
    __shared__ __align__(16) unsigned short Bs[128][72];
    const int tid = threadIdx.x;
    const int bm = blockIdx.x * 64;
    const int wid = tid >> 6, lane = tid & 63;
    const int wr = wid & 1, wc = wid >> 1;      // 2x2 wave grid: 32 rows x 64 cols each
    const int l15 = lane & 15, l4 = lane >> 4;

    f32x4 acc[2][4] = {};

    for (int k0 = 0; k0 < K; k0 += 64) {
        {
            int r = tid >> 2, q = tid & 3;      // 16 bf16 per thread, vectorized
            int gm = bm + r;
            if (gm < M) {
                const uint4* g = (const uint4*)(A + (size_t)gm * lda + k0 + q * 16);
                *(uint4*)&As[r][q * 16] = g[0];
                *(uint4*)&As[r][q * 16 + 8] = g[1];
            } else {
                uint4 z = {0, 0, 0, 0};
                *(uint4*)&As[r][q * 16] = z;
                *(uint4*)&As[r][q * 16 + 8] = z;
            }
        }
        {
            int col = tid >> 1, hf = tid & 1;   // 32 bf16 per thread from Bt[col][k0+hf*32..]
            const uint4* g = (const uint4*)(Bt + (size_t)col * K + k0 + hf * 32);
            #pragma unroll
            for (int j = 0; j < 4; ++j)
                *(uint4*)&Bs[col][hf * 32 + j * 8] = g[j];
        }
        __syncthreads();
        #pragma unroll
        for (int kk = 0; kk < 2; ++kk) {
            short8 a[2], b[4];
            #pragma unroll
            for (int mi = 0; mi < 2; ++mi)
                a[mi] = *(const short8*)&As[wr * 32 + mi * 16 + l15][kk * 32 + l4 * 8];
            #pragma unroll
            for (int ni = 0; ni < 4; ++ni)
                b[ni] = *(const short8*)&Bs[wc * 64 + ni * 16 + l15][kk * 32 + l4 * 8];
            #pragma unroll
            for (int mi = 0; mi < 2; ++mi)
                #pragma unroll
                for (int ni = 0; ni < 4; ++ni)
                    acc[mi][ni] = __builtin_amdgcn_mfma_f32_16x16x32_bf16(
                        a[mi], b[ni], acc[mi][ni], 0, 0, 0);
        }
        __syncthreads();
    }

    // epilogue: C/D layout col=lane&15, row=(lane>>4)*4+reg  [m89-verified]
    #pragma unroll
    for (int mi = 0; mi < 2; ++mi) {
        #pragma unroll
        for (int r = 0; r < 4; ++r) {
            int grow = bm + wr * 32 + mi * 16 + l4 * 4 + r;
            if (grow >= M) continue;
            float rs = dsc.rowscale ? dsc.rowscale[grow] : 1.f;
            float al = dsc.alast ? dsc.alast[grow] : 0.f;
            #pragma unroll
            for (int ni = 0; ni < 4; ++ni) {
                int gcol = wc * 64 + ni * 16 + l15;
                float v = acc[mi][ni][r];
                if (dsc.wlast) v += al * dsc.wlast[gcol];
                if (dsc.bias) v += dsc.bias[gcol];
                v *= rs;
                if (relu) v = fmaxf(v, 0.f);
                dsc.out[(size_t)grow * HD + gcol] = f2b(v);
            }
        }
    }
}

// ---------------- batched CSR gather: wide loads ----------------
struct GatherDesc {
    const unsigned short* msgA; const unsigned short* sortedA;
    const int* offA; const float* rsqA;
    const unsigned short* msgB; const unsigned short* sortedB;  // null if single
    const int* offB; const float* rsqB;
    const float* bias; void* out;
};
struct GatherBatch { GatherDesc d[4]; };

__device__ __forceinline__ void accum8(uint4 v, float* acc) {
    acc[0] += b2f(v.x & 0xffffu); acc[1] += b2f(v.x >> 16);
    acc[2] += b2f(v.y & 0xffffu); acc[3] += b2f(v.y >> 16);
    acc[4] += b2f(v.z & 0xffffu); acc[5] += b2f(v.z >> 16);
    acc[6] += b2f(v.w & 0xffffu); acc[7] += b2f(v.w >> 16);
}

__device__ __forceinline__ void gather_seg(
    const unsigned short* __restrict__ msg, const unsigned short* __restrict__ sorted,
    int beg, int end, int sub, int lbyte, float* acc)
{
    const char* mbase = (const char*)msg;
    int e = beg;
    for (; e + 16 <= end; e += 16) {            // full chunks: 16 edges, 4 loads/lane
        uint4 v[4];
        #pragma unroll
        for (int r = 0; r < 4; ++r) {
            int s = sorted[e + r * 4 + sub];
            v[r] = *(const uint4*)(mbase + (size_t)s * 256 + lbyte);
        }
        #pragma unroll
        for (int r = 0; r < 4; ++r) accum8(v[r], acc);
    }
    if (e < end) {                               // masked tail chunk
        #pragma unroll
        for (int r = 0; r < 4; ++r) {
            int idx = e + r * 4 + sub;
            if (idx < end) {
                int s = sorted[idx];
                uint4 v = *(const uint4*)(mbase + (size_t)s * 256 + lbyte);
                accum8(v, acc);
            }
        }
    }
}

template<int OUT_BF16>
__global__ __launch_bounds__(256) void gather_kernel(GatherBatch batch, int n)
{
    const GatherDesc d = batch.d[blockIdx.y];
    int node = blockIdx.x * 4 + (threadIdx.x >> 6);   // wave-uniform
    if (node >= n) return;
    int lane = threadIdx.x & 63;
    int sub = lane >> 4;
    int l16 = lane & 15;
    int lbyte = l16 * 16;

    float comb[8];
    {
        float acc[8] = {};
        gather_seg(d.msgA, d.sortedA, d.offA[node], d.offA[node + 1], sub, lbyte, acc);
        float rA = d.rsqA[node];
        if (d.msgB) {
            float acc2[8] = {};
            gather_seg(d.msgB, d.sortedB, d.offB[node], d.offB[node + 1], sub, lbyte, acc2);
            float rB = d.rsqB[node];
            #pragma unroll
            for (int c = 0; c < 8; ++c) comb[c] = acc[c] * rA + acc2[c] * rB;
        } else {
            #pragma unroll
            for (int c = 0; c < 8; ++c) comb[c] = acc[c] * rA;
        }
    }
    #pragma unroll
    for (int c = 0; c < 8; ++c) {
        comb[c] += __shfl_xor(comb[c], 16);
        comb[c] += __shfl_xor(comb[c], 32);
    }
    if (sub == 0) {
        const float* bptr = d.bias + l16 * 8;
        float4 b0 = *(const float4*)bptr;
        float4 b1 = *(const float4*)(bptr + 4);
        float o[8] = {comb[0] + b0.x, comb[1] + b0.y, comb[2] + b0.z, comb[3] + b0.w,
                      comb[4] + b1.x, comb[5] + b1.y, comb[6] + b1.z, comb[7] + b1.w};
        #pragma unroll
        for (int c = 0; c < 8; ++c) o[c] = fmaxf(o[c], 0.f);
        if (OUT_BF16) {
            uint4 pv;
            pv.x = ((unsigned int)f2b(o[1]) << 16) | f2b(o[0]);
            pv.y = ((unsigned int)f2b(o[3]) << 16) | f2b(o[2]);
            pv.z = ((unsigned int)f2b(o[5]) << 16) | f2b(o[4]);
            pv.w = ((unsigned int)f2b(o[7]) << 16) | f2b(o[6]);
            *(uint4*)((char*)d.out + (size_t)node * 256 + lbyte) = pv;
        } else {
            float4 f0 = {o[0], o[1], o[2], o[3]};
            float4 f1 = {o[4], o[5], o[6], o[7]};
            float4* op = (float4*)((char*)d.out + (size_t)node * 512 + (size_t)l16 * 32);
            op[0] = f0; op[1] = f1;
        }
    }
}

extern "C" void kernel_launch(void* const* d_in, const int* in_sizes, int n_in,
                              void* d_out, int out_size, void* d_ws, size_t ws_size,
                              hipStream_t stream)
{
    const float* feat[4] = {(const float*)d_in[0], (const float*)d_in[1],
                            (const float*)d_in[2], (const float*)d_in[3]};
    const int* src_all = (const int*)d_in[4];
    const int* dst_all = (const int*)d_in[5];
    const float* Wp  = (const float*)d_in[6];
    const float* bp  = (const float*)d_in[7];
    const float* Wc1 = (const float*)d_in[8];
    const float* bc1 = (const float*)d_in[9];
    const float* Wc2 = (const float*)d_in[10];
    const float* bc2 = (const float*)d_in[11];

    const int N = in_sizes[0] / INF;      // 50000  (< 65536: ushort ids)
    const int E = in_sizes[4] / 5;        // 1,600,000
    const int W = (E + NBUCKET - 1) / NBUCKET;   // 25000 (< 65536: ushort pos_local)

    // etypes: k -> (src_type, dst_type): (0,1) (1,3) (3,2) (0,2) (2,0)
    const int st_[5] = {0, 1, 3, 0, 2};

    // ---- workspace layout (256B-aligned) ----
    char* w = (char*)d_ws;
    auto take = [&](size_t bytes) { char* p = w; w += (bytes + 255) & ~(size_t)255; return p; };
    int*   cnt_dst = (int*)take(5 * (size_t)N * 4);
    float* rsq_out = (float*)take(5 * (size_t)N * 4);
    float* rsq_in  = (float*)take(5 * (size_t)N * 4);
    int*   off     = (int*)take(5 * (size_t)(N + 1) * 4);
    unsigned short* sorted = (unsigned short*)take(5 * (size_t)E * 2);  // 16 MB, live whole pass
    float* alast   = (float*)take(4 * (size_t)N * 4);
    unsigned short* WpT = (unsigned short*)take(4 * 128 * 384 * 2);
    unsigned short* WcT = (unsigned short*)take(2 * 5 * 128 * 128 * 2);
    float* cbias   = (float*)take(2 * 4 * 128 * 4);
    int*   cursor  = (int*)take(5 * NBUCKET * 4);

    const size_t pr_bytes  = 10u * NWG * (size_t)N * 2 + 5 * (size_t)E * 2;  // partial+rank (32MB)
    const size_t stg_bytes = 5 * (size_t)NBUCKET * (size_t)W * 4;            // staging (32MB)
    const size_t blob_sz   = 4 * (size_t)N * 384 * 2;                        // featB (153.6MB)
    size_t fixed_used = (size_t)(w - (char*)d_ws);
    bool roomy  = ws_size >= fixed_used + pr_bytes + blob_sz + (1u << 20);
    bool staged = ws_size >= fixed_used + pr_bytes + stg_bytes + blob_sz + (1u << 20);

    unsigned short *partial, *rank_local, *featB, *msg;
    unsigned int* staging = nullptr;
    if (roomy) {
        partial    = (unsigned short*)take(10u * NWG * (size_t)N * 2);
        rank_local = (unsigned short*)take(5 * (size_t)E * 2);
        if (staged) staging = (unsigned int*)take(stg_bytes);
        char* blob = (char*)take(blob_sz);
        featB = (unsigned short*)blob;
        msg   = (unsigned short*)blob;   // overlays featB after proj
    } else {
        char* blob = (char*)take(blob_sz);
        partial    = (unsigned short*)blob;
        rank_local = (unsigned short*)(blob + 10u * NWG * (size_t)N * 2);
        featB      = (unsigned short*)blob;
        msg        = (unsigned short*)(blob + 32u * 1024 * 1024);
    }
    // h0 in d_out lower half (bf16), h1 in d_out upper half (bf16); both dead
    // before layer-2 gathers write f32 over the full d_out.
    unsigned short* h0 = (unsigned short*)d_out;
    unsigned short* h1 = (unsigned short*)d_out + 4 * (size_t)N * HD;

    const int gblk = (N + 63) / 64;

    prep_weights_kernel<<<512, 256, 0, stream>>>(Wp, Wc1, Wc2, bc1, bc2, WpT, WcT, cbias);

    // hist (160 blocks) || convert (512 blocks if roomy) in one dispatch
    hist_conv_kernel<<<roomy ? HIST_BLOCKS + 512 : HIST_BLOCKS, 1024, 0, stream>>>(
        src_all, dst_all, partial, rank_local, E, N,
        feat[0], feat[1], feat[2], feat[3], (unsigned int*)featB, alast);
    reduce_kernel<<<(10 * N + 255) / 256, 256, 0, stream>>>(partial, cnt_dst, rsq_out, rsq_in, N);
    scan_kernel<<<5, 1024, 0, stream>>>(cnt_dst, off, N);

    if (staged) {
        hipMemsetAsync(cursor, 0, 5 * NBUCKET * 4, stream);
        int wgPerEt = (E + BK_CHUNK - 1) / BK_CHUNK;
        bin_kernel<<<5 * wgPerEt, 1024, 0, stream>>>(
            src_all, dst_all, off, partial, rank_local, cursor, staging, E, N, W, wgPerEt);
        unbucket_kernel<<<5 * NBUCKET, 256, 0, stream>>>(staging, cursor, sorted, E, W);
    } else {
        permute_kernel<<<2048, 256, 0, stream>>>(src_all, dst_all, off, partial, rank_local,
                                                 sorted, E, N);
    }
    if (!roomy)
        convert_kernel<<<2048, 256, 0, stream>>>(feat[0], feat[1], feat[2], feat[3],
                                                 (unsigned int*)featB, alast, N);

    // ---- input projections (batched over 4 types) ----
    {
        GemmBatch pb = {};
        for (int t = 0; t < 4; ++t) {
            pb.d[t].A = featB + (size_t)t * N * 384;
            pb.d[t].Bt = WpT + (size_t)t * 128 * 384;
            pb.d[t].bias = bp + (size_t)t * HD;
            pb.d[t].rowscale = nullptr;
            pb.d[t].alast = alast + (size_t)t * N;
            pb.d[t].wlast = Wp + (size_t)t * INF * HD + 384 * HD;
            pb.d[t].out = h0 + (size_t)t * N * HD;
        }
        gemm_mfma_kernel<<<dim3(gblk, 4), 256, 0, stream>>>(pb, 384, N, 384, 1);
    }

    // ---- 2 hetero conv layers ----
    for (int layer = 0; layer < 2; ++layer) {
        const unsigned short* hin = layer ? h1 : h0;
        const unsigned short* WT = WcT + (size_t)layer * 5 * 128 * 128;
        const float* cb = cbias + (size_t)layer * 4 * 128;

        // 5 independent conv GEMMs in one dispatch
        {
            GemmBatch cbch = {};
            for (int k = 0; k < 5; ++k) {
                cbch.d[k].A = hin + (size_t)st_[k] * N * HD;
                cbch.d[k].Bt = WT + (size_t)k * 128 * 128;
                cbch.d[k].bias = nullptr;
                cbch.d[k].rowscale = rsq_out + (size_t)k * N;
                cbch.d[k].alast = nullptr;
                cbch.d[k].wlast = nullptr;
                cbch.d[k].out = msg + (size_t)k * N * HD;
            }
            gemm_mfma_kernel<<<dim3(gblk, 5), 256, 0, stream>>>(cbch, HD, N, 128, 0);
        }

        // 4 gathers (k2+k3 dual into t2) in one dispatch
        {
            auto S = [&](int k) { return sorted + (size_t)k * E; };
            auto O = [&](int k) { return off + (size_t)k * (N + 1); };
            auto R = [&](int k) { return rsq_in + (size_t)k * N; };
            auto M_ = [&](int k) { return msg + (size_t)k * N * HD; };
            const int ksA[4] = {0, 1, 2, 4};
            const int dt [4] = {1, 3, 2, 0};
            GatherBatch gb = {};
            for (int y = 0; y < 4; ++y) {
                int k = ksA[y];
                gb.d[y].msgA = M_(k); gb.d[y].sortedA = S(k);
                gb.d[y].offA = O(k);  gb.d[y].rsqA = R(k);
                gb.d[y].msgB = nullptr; gb.d[y].sortedB = nullptr;
                gb.d[y].offB = nullptr; gb.d[y].rsqB = nullptr;
                gb.d[y].bias = cb + (size_t)dt[y] * HD;
                if (layer == 0)
                    gb.d[y].out = h1 + (size_t)dt[y] * N * HD;
                else
                    gb.d[y].out = (float*)d_out + (size_t)dt[y] * N * HD;
            }
            gb.d[2].msgB = M_(3); gb.d[2].sortedB = S(3);
            gb.d[2].offB = O(3);  gb.d[2].rsqB = R(3);
            const int gg = (N + 3) / 4;
            if (layer == 0)
                gather_kernel<1><<<dim3(gg, 4), 256, 0, stream>>>(gb, N);
            else
                gather_kernel<0><<<dim3(gg, 4), 256, 0, stream>>>(gb, N);
        }
    }
}